// Round 5
// baseline (517.551 us; speedup 1.0000x reference)
//
#include <hip/hip_runtime.h>
#include <stdint.h>
#include <stddef.h>

#define B_ 4
#define S_ 2048
#define D_ 2048
#define NH 16
#define NKV 4
#define HD 128
#define QKV_N 3072
#define ROWS (B_*S_)

typedef unsigned short u16;
typedef __attribute__((ext_vector_type(8))) unsigned short u16x8;
typedef __attribute__((ext_vector_type(8))) __bf16 bf16x8;
typedef __attribute__((ext_vector_type(4))) float f32x4;

__device__ __forceinline__ u16 f2bf(float f) {
  unsigned u = __builtin_bit_cast(unsigned, f);
  return (u16)((u + 0x7fffu + ((u >> 16) & 1u)) >> 16);
}
__device__ __forceinline__ float bf2f(u16 h) {
  return __builtin_bit_cast(float, (unsigned)h << 16);
}
__device__ __forceinline__ f32x4 mfma16(u16x8 a, u16x8 b, f32x4 c) {
  return __builtin_amdgcn_mfma_f32_16x16x32_bf16(
      __builtin_bit_cast(bf16x8, a), __builtin_bit_cast(bf16x8, b), c, 0, 0, 0);
}
__device__ __forceinline__ void gld16(const void* g, void* l) {
  __builtin_amdgcn_global_load_lds(
      (const __attribute__((address_space(1))) void*)g,
      (__attribute__((address_space(3))) void*)l, 16, 0, 0);
}

// ---------- elementwise cast x -> bf16 ----------
__global__ __launch_bounds__(256) void k_cast_x(const float* __restrict__ x, u16* __restrict__ xb) {
  int i = blockIdx.x * 256 + threadIdx.x;
  float4 v = ((const float4*)x)[i];
  union { u16 u[4]; uint2 p; } o;
  o.u[0] = f2bf(v.x); o.u[1] = f2bf(v.y); o.u[2] = f2bf(v.z); o.u[3] = f2bf(v.w);
  ((uint2*)xb)[i] = o.p;
}

// ---------- tiled transpose+cast: w[K][N] fp32 -> wt[N][K(=2048 pitch)] bf16 ----------
__global__ __launch_bounds__(256) void k_wt(const float* __restrict__ w, u16* __restrict__ wt, int K, int N) {
  __shared__ float tile[32][33];
  int kb = blockIdx.y * 32, nb = blockIdx.x * 32;
  int tx = threadIdx.x, ty = threadIdx.y;
#pragma unroll
  for (int j = 0; j < 32; j += 8)
    tile[ty + j][tx] = w[(size_t)(kb + ty + j) * N + nb + tx];
  __syncthreads();
#pragma unroll
  for (int j = 0; j < 32; j += 8)
    wt[(size_t)(nb + ty + j) * K + kb + tx] = f2bf(tile[tx][ty + j]);
}

// ---------- 256x256 GEMM, FAT-WAVE geometry: 4 waves (2x2), wave-tile 128x128 ----------
// Rounds 1-4 proved the 8-wave/128x64 geometry is resource-walled at ~1160 cyc/phase:
// MFMA 621 + LDS ~700 co-critical (A re-read x4 by 4 wn-waves), and regfile caps
// occupancy at 8 waves/CU. This geometry halves LDS re-reads (A x2, B x2: 64 KB/K32
// vs 96) and doubles per-SIMD MFMA per phase (64 instr = 1242 cyc) so LDS fits
// UNDER the MFMA cluster. 1 wave/SIMD: no lockstep partner to wait for; compiler
// emits fine-grained lgkmcnt to stream ds_reads into the MFMA cluster (m97 r109).
// No setprio (nothing to arbitrate at 1 wave/SIMD, m190), no sched_barrier pinning.
// Staging: 4-slot k-half ring per operand ([256][32] bf16 = 16 KB slots, 128 KiB),
// slot(t,kh)=(2t+kh)&3, stage (t+1,kh) in phase (t,kh) -> slot (2t+2+kh)&3;
// vmcnt(8) once per phase confirms the half staged last phase (read next phase).
// Proven conflict-free chunk swizzle kept: LDS pos = chunk ^ ((row>>1)&3),
// source pre-swizzled. Accumulation order over K unchanged (bitwise-identical).

#define STG(GP, KK, SS, LB) do {                                             \
    _Pragma("unroll") for (int j_ = 0; j_ < 4; ++j_)                         \
      gld16(GP + (size_t)(j_ * 64 + r0) * 2048 + (KK) + coff,                \
            LB + (SS) * 8192 + j_ * 2048 + stl);                             \
  } while (0)

#define PH(RS, SS, KN) do {                                                  \
    STG(Ag, KN, SS, As);                                                     \
    STG(Bg, KN, SS, Bs);                                                     \
    const u16* Ap_ = As + (RS) * 8192;                                       \
    const u16* Bp_ = Bs + (RS) * 8192;                                       \
    u16x8 af_[8], bf_[8];                                                    \
    _Pragma("unroll") for (int i_ = 0; i_ < 8; ++i_)                         \
      af_[i_] = *(const u16x8*)(Ap_ + arow0 + i_ * 512);                     \
    _Pragma("unroll") for (int i_ = 0; i_ < 8; ++i_)                         \
      bf_[i_] = *(const u16x8*)(Bp_ + brow0 + i_ * 512);                     \
    _Pragma("unroll") for (int m_ = 0; m_ < 8; ++m_)                         \
      _Pragma("unroll") for (int n_ = 0; n_ < 8; ++n_)                       \
        acc[m_][n_] = mfma16(af_[m_], bf_[n_], acc[m_][n_]);                 \
    asm volatile("s_waitcnt vmcnt(8)" ::: "memory");                         \
    asm volatile("s_barrier" ::: "memory");                                  \
  } while (0)

template<int NT, bool F32OUT>
__global__ __launch_bounds__(256, 1) void k_gemm(const u16* __restrict__ A, const u16* __restrict__ Bt,
                                                 void* __restrict__ C) {
  __shared__ u16 As[4 * 8192];   // 64 KiB: 4 k-half slots [256][32]
  __shared__ u16 Bs[4 * 8192];   // 64 KiB
  int id = blockIdx.x;
  int nwg = gridDim.x;                        // divisible by 8 for both grids
  id = (id & 7) * (nwg >> 3) + (id >> 3);     // XCD-contiguous (bijective: nwg%8==0)
  const int gx = NT / 256;
  int mb = (id / gx) * 256, nb = (id % gx) * 256;

  int t = threadIdx.x;
  int l = t & 63, L16 = l & 15, quad = l >> 4;
  int w = t >> 6, wm = w >> 1, wn = w & 1;    // 2x2 wave grid, wave tile 128x128
  const int schunk = 8 * (quad ^ ((L16 >> 1) & 3));  // quad-pass-balanced read chunk
  const int arow0 = (wm * 128 + L16) * 32 + schunk;
  const int brow0 = (wn * 128 + L16) * 32 + schunk;
  const int r0 = t >> 2;                      // staging row within 64-row sweep
  const int coff = 8 * ((t & 3) ^ ((r0 >> 1) & 3));   // inverse-swizzled global chunk
  const int stl = (t & 192) * 8;              // wave-uniform LDS base (HW adds lane*16B)

  const u16* Ag = A + (size_t)mb * 2048;
  const u16* Bg = Bt + (size_t)nb * 2048;
  f32x4 acc[8][8] = {};

  // prologue: (0,k0)->slot0, (0,k1)->slot1; vmcnt(8) confirms (0,k0)
  STG(Ag, 0, 0, As);  STG(Bg, 0, 0, Bs);
  STG(Ag, 32, 1, As); STG(Bg, 32, 1, Bs);
  asm volatile("s_waitcnt vmcnt(8)" ::: "memory");
  asm volatile("s_barrier" ::: "memory");

#pragma unroll 1
  for (int tp = 0; tp < 16; ++tp) {
    int e = 2 * tp, o = 2 * tp + 1;
    int ke = ((e + 1) & 31) * 64;            // (e+1) tile k-col base (wraps tail)
    int ko = ((o + 1) & 31) * 64;
    PH(0, 2, ke);        // (e,k0): read s0, stage (e+1,k0)->s2
    PH(1, 3, ke + 32);   // (e,k1): read s1, stage (e+1,k1)->s3
    PH(2, 0, ko);        // (o,k0): read s2, stage (o+1,k0)->s0
    PH(3, 1, ko + 32);   // (o,k1): read s3, stage (o+1,k1)->s1
  }
  asm volatile("s_waitcnt vmcnt(0)" ::: "memory");  // drain tail garbage stages

#pragma unroll
  for (int m = 0; m < 8; ++m)
#pragma unroll
    for (int n = 0; n < 8; ++n)
#pragma unroll
      for (int r = 0; r < 4; ++r) {
        int row = mb + wm * 128 + m * 16 + quad * 4 + r;
        int col = nb + wn * 128 + n * 16 + L16;
        if constexpr (F32OUT)
          ((float*)C)[(size_t)row * NT + col] = acc[m][n][r];
        else
          ((u16*)C)[(size_t)row * NT + col] = f2bf(acc[m][n][r]);
      }
}

// ---------- RoPE + scatter; Q pre-scaled by log2(e)/sqrt(HD) ----------
__global__ __launch_bounds__(256) void k_rope(const u16* __restrict__ qkv, const float* __restrict__ fc,
                                              const float* __restrict__ fs, u16* __restrict__ Q,
                                              u16* __restrict__ Kk) {
  const float SC = 0.1275174214f;  // log2(e)/sqrt(128), folded into Q
  int row = blockIdx.x;            // b*S + s
  int b = row >> 11, s = row & 2047;
  int t = threadIdx.x;
#pragma unroll
  for (int j = 0; j < 5; ++j) {
    int p = t + j * 256;           // pair index, 0..1279
    int i = p & 63;
    float c = fc[s * 64 + i], sn = fs[s * 64 + i];
    if (p < 1024) {
      int h = p >> 6;
      unsigned pr = *(const unsigned*)(qkv + (size_t)row * QKV_N + h * 128 + 2 * i);
      float xr = bf2f((u16)(pr & 0xffff)), xi = bf2f((u16)(pr >> 16));
      size_t o = (((size_t)(b * NH + h) * S_) + s) * HD + 2 * i;
      unsigned out = (unsigned)f2bf((xr * c - xi * sn) * SC) |
                     ((unsigned)f2bf((xr * sn + xi * c) * SC) << 16);
      *(unsigned*)(Q + o) = out;
    } else {
      int kh = (p - 1024) >> 6;
      unsigned pr = *(const unsigned*)(qkv + (size_t)row * QKV_N + 2048 + kh * 128 + 2 * i);
      float xr = bf2f((u16)(pr & 0xffff)), xi = bf2f((u16)(pr >> 16));
      size_t o = (((size_t)(b * NKV + kh) * S_) + s) * HD + 2 * i;
      unsigned out = (unsigned)f2bf(xr * c - xi * sn) | ((unsigned)f2bf(xr * sn + xi * c) << 16);
      *(unsigned*)(Kk + o) = out;
    }
  }
}

// ---------- V transpose: coalesced loads -> swizzled LDS -> u32-pair transposed reads ----------
__global__ __launch_bounds__(256) void k_vt(const u16* __restrict__ qkv, u16* __restrict__ Vt) {
  __shared__ u16 tile[64 * 128];       // [s][d], chunk-swizzled: chunk ^= s&15
  int blk = blockIdx.x;                // b*128 + kh*32 + sb
  int sb = blk & 31, kh = (blk >> 5) & 3, b = blk >> 7;
  int t = threadIdx.x;
  int s0 = sb * 64;
#pragma unroll
  for (int i = 0; i < 4; ++i) {
    int lin = i * 256 + t;
    int row = lin >> 4, c = lin & 15;
    u16x8 v = *(const u16x8*)(qkv + (size_t)(b * S_ + s0 + row) * QKV_N + 2560 + kh * HD + c * 8);
    *(u16x8*)(tile + row * 128 + ((c ^ (row & 15)) * 8)) = v;
  }
  __syncthreads();
#pragma unroll
  for (int i = 0; i < 2; ++i) {
    int u = i * 256 + t;
    int p = u >> 3, o = u & 7;         // d = 2p, 2p+1 ; s = o*8 .. o*8+7
    u16 lo[8], hi[8];
#pragma unroll
    for (int j = 0; j < 8; ++j) {
      int s = o * 8 + j;
      int cs = (p >> 2) ^ (s & 15);
      unsigned v = *(const unsigned*)(tile + s * 128 + cs * 8 + (p & 3) * 2);
      lo[j] = (u16)(v & 0xffff); hi[j] = (u16)(v >> 16);
    }
    size_t ob = ((size_t)(b * NKV + kh) * HD + 2 * p) * S_ + s0 + o * 8;
    *(u16x8*)(Vt + ob)      = *(u16x8*)lo;
    *(u16x8*)(Vt + ob + S_) = *(u16x8*)hi;
  }
}

// ---------- flash attention v6: R2 skeleton + S^T compute (b64 P writes) + hoisted LDS addrs ----------
__global__ __launch_bounds__(256) void k_attn(const u16* __restrict__ Q, const u16* __restrict__ Kg,
                                              const u16* __restrict__ Vt, u16* __restrict__ O) {
  int bx = blockIdx.x;
  int bh = bx >> 3, pr = bx & 7;
  int b = bh >> 4, h = bh & 15, kh = h >> 2;
  int t = threadIdx.x;
  int w = t >> 6, l = t & 63, L = l & 15, quad = l >> 4;

  __shared__ u16 Ks[64 * 128];         // [key][d], chunk ^= key&7
  __shared__ u16 Vs[128 * 64];         // [d][key], chunk ^= d&7
  __shared__ u16 Ps[4][32 * 72];       // per-wave P[q][key], pitch 72
  u16* Pw = &Ps[w][0];

  const u16* Qh = Q  + ((size_t)(b * NH  + h ) * S_) * HD;
  const u16* Kh = Kg + ((size_t)(b * NKV + kh) * S_) * HD;
  const u16* Vh = Vt + ((size_t)(b * NKV + kh) * HD) * S_;

  u16x8 ones;                          // bf16 1.0 B-fragment -> row sums in acc[.][8]
#pragma unroll
  for (int i = 0; i < 8; ++i) ones[i] = 0x3F80;

  // ---- hoisted LDS fragment offsets (u16 units; loop-invariant, imm offsets inside) ----
  int koff[4], voff[2];
#pragma unroll
  for (int kk = 0; kk < 4; ++kk) koff[kk] = 128 * L + 8 * ((4 * kk + quad) ^ (L & 7));
#pragma unroll
  for (int kc = 0; kc < 2; ++kc) voff[kc] = 64 * L + 8 * ((4 * kc + quad) ^ (L & 7));
  const int pread  = 72 * L + 8 * quad;   // + 1152*m + 32*kc (imm)
  const int pwrite = 72 * L + 4 * quad;   // + 1152*m + 16*n  (imm)

  // ---- hoisted staging offsets ----
  int kgo[4], vgo[4], klo[4], vlo[4];
#pragma unroll
  for (int i = 0; i < 4; ++i) {
    int lin = i * 256 + t;
    int row = lin >> 4, c = lin & 15;
    kgo[i] = row * HD + ((c ^ (row & 7)) * 8);
    int d = lin >> 3, c2 = lin & 7;
    vgo[i] = d * S_ + ((c2 ^ (d & 7)) * 8);
    klo[i] = (i * 256 + (t & 192)) * 8;
    vlo[i] = (i * 256 + (t & 192)) * 8;
  }

#pragma unroll 1
  for (int half = 0; half < 2; ++half) {
    int qb = half ? (15 - pr) : pr;
    int q0 = qb * 128 + w * 32;        // this wave's 32 query rows

    u16x8 qf[2][4];
#pragma unroll
    for (int m = 0; m < 2; ++m)
#pragma unroll
      for (int kk = 0; kk < 4; ++kk)
        qf[m][kk] = *(const u16x8*)(Qh + (size_t)(q0 + m * 16 + L) * HD + kk * 32 + quad * 8);

    f32x4 acc[2][9] = {};
    int ktiles = 2 * qb + 2;
#pragma unroll 1
    for (int kt = 0; kt < ktiles; ++kt) {
      int kbase = kt * 64;
      __syncthreads();
      const u16* Kt = Kh + (size_t)kbase * HD;
      const u16* Vg = Vh + kbase;
#pragma unroll
      for (int i = 0; i < 4; ++i) gld16(Kt + kgo[i], Ks + klo[i]);
#pragma unroll
      for (int i = 0; i < 4; ++i) gld16(Vg + vgo[i], Vs + vlo[i]);
      __syncthreads();
      if (kbase > q0 + 31) continue;   // fully masked for this wave; barriers stay uniform

      bool needMask = (kbase + 63 > q0);
      // S^T = K Q^T : A=K-frag, B=Q-frag -> lane holds 4 consecutive keys (rows), col=q
#pragma unroll
      for (int n = 0; n < 4; ++n) {
        f32x4 s0v = {}, s1v = {};
#pragma unroll
        for (int kk = 0; kk < 4; ++kk) {
          u16x8 kf = *(const u16x8*)(Ks + koff[kk] + 2048 * n);
          s0v = mfma16(kf, qf[0][kk], s0v);
          s1v = mfma16(kf, qf[1][kk], s1v);
        }
        // exp2 + mask + packed b64 P store: keys 16n+4quad+r, q = q0+16m+L
#pragma unroll
        for (int m = 0; m < 2; ++m) {
          f32x4 sv = m ? s1v : s0v;
          int qrow = q0 + m * 16 + L;
          unsigned eu[4];
#pragma unroll
          for (int r = 0; r < 4; ++r) {
            float e = exp2f(sv[r]);
            if (needMask) {
              int key = kbase + n * 16 + quad * 4 + r;
              e = (key <= qrow) ? e : 0.0f;
            }
            eu[r] = __builtin_bit_cast(unsigned, e);
          }
          uint2 pk;
          pk.x = __builtin_amdgcn_perm(eu[1], eu[0], 0x07060302u);  // bf16(e0)|bf16(e1)<<16 (trunc)
          pk.y = __builtin_amdgcn_perm(eu[3], eu[2], 0x07060302u);
          *(uint2*)(Pw + pwrite + 1152 * m + 16 * n) = pk;
        }
      }
      // O += P V ; row sums via register ones fragment into acc[.][8] (wave-private P)
#pragma unroll
      for (int kc = 0; kc < 2; ++kc) {
        u16x8 pf0 = *(const u16x8*)(Pw + pread + 32 * kc);
        u16x8 pf1 = *(const u16x8*)(Pw + pread + 1152 + 32 * kc);
#pragma unroll
        for (int nt = 0; nt < 8; ++nt) {
          u16x8 vf = *(const u16x8*)(Vs + voff[kc] + 1024 * nt);
          acc[0][nt] = mfma16(pf0, vf, acc[0][nt]);
          acc[1][nt] = mfma16(pf1, vf, acc[1][nt]);
        }
        acc[0][8] = mfma16(pf0, ones, acc[0][8]);
        acc[1][8] = mfma16(pf1, ones, acc[1][8]);
      }
    }
    // epilogue: normalize by ones-column sums (acc[m][8]), write [b][s][h*128+d]
#pragma unroll
    for (int m = 0; m < 2; ++m)
#pragma unroll
      for (int r = 0; r < 4; ++r) {
        float inv = 1.0f / acc[m][8][r];
        int qrow = q0 + m * 16 + quad * 4 + r;
#pragma unroll
        for (int nt = 0; nt < 8; ++nt) {
          int col = h * HD + nt * 16 + L;
          O[(size_t)(b * S_ + qrow) * D_ + col] = f2bf(acc[m][nt][r] * inv);
        }
      }
  }
}

extern "C" void kernel_launch(void* const* d_in, const int* in_sizes, int n_in,
                              void* d_out, int out_size, void* d_ws, size_t ws_size,
                              hipStream_t stream) {
  const float* x  = (const float*)d_in[0];
  const float* fc = (const float*)d_in[1];
  const float* fs = (const float*)d_in[2];
  const float* wq = (const float*)d_in[3];
  const float* wk = (const float*)d_in[4];
  const float* wv = (const float*)d_in[5];
  const float* wo = (const float*)d_in[6];
  float* out = (float*)d_out;

  u16* p = (u16*)d_ws;
  u16* xb    = p; p += (size_t)ROWS * D_;
  u16* wqkvT = p; p += (size_t)QKV_N * D_;
  u16* woT   = p; p += (size_t)D_ * D_;
  u16* qkv   = p; p += (size_t)ROWS * QKV_N;
  u16* Qr    = p; p += (size_t)ROWS * (NH * HD);
  u16* Kr    = p; p += (size_t)ROWS * (NKV * HD);
  u16* Vtr   = p; p += (size_t)ROWS * (NKV * HD);
  u16* AO    = p; p += (size_t)ROWS * D_;

  k_cast_x<<<dim3(ROWS * D_ / 1024), dim3(256), 0, stream>>>(x, xb);
  k_wt<<<dim3(64, 64), dim3(32, 8), 0, stream>>>(wq, wqkvT, 2048, 2048);
  k_wt<<<dim3(16, 64), dim3(32, 8), 0, stream>>>(wk, wqkvT + (size_t)2048 * 2048, 2048, 512);
  k_wt<<<dim3(16, 64), dim3(32, 8), 0, stream>>>(wv, wqkvT + (size_t)2560 * 2048, 2048, 512);
  k_wt<<<dim3(64, 64), dim3(32, 8), 0, stream>>>(wo, woT, 2048, 2048);
  k_gemm<QKV_N, false><<<dim3((QKV_N / 256) * (ROWS / 256)), dim3(256), 0, stream>>>(xb, wqkvT, qkv);
  k_rope<<<dim3(ROWS), dim3(256), 0, stream>>>(qkv, fc, fs, Qr, Kr);
  k_vt<<<dim3(B_ * NKV * (S_ / 64)), dim3(256), 0, stream>>>(qkv, Vtr);
  k_attn<<<dim3(64 * 8), dim3(256), 0, stream>>>(Qr, Kr, Vtr, AO);
  k_gemm<D_, true><<<dim3((D_ / 256) * (ROWS / 256)), dim3(256), 0, stream>>>(AO, woT, out);
}

// Round 6
// 446.390 us; speedup vs baseline: 1.1594x; 1.1594x over previous
//
#include <hip/hip_runtime.h>
#include <stdint.h>
#include <stddef.h>

#define B_ 4
#define S_ 2048
#define D_ 2048
#define NH 16
#define NKV 4
#define HD 128
#define QKV_N 3072
#define ROWS (B_*S_)

typedef unsigned short u16;
typedef __attribute__((ext_vector_type(8))) unsigned short u16x8;
typedef __attribute__((ext_vector_type(8))) __bf16 bf16x8;
typedef __attribute__((ext_vector_type(4))) float f32x4;

__device__ __forceinline__ u16 f2bf(float f) {
  unsigned u = __builtin_bit_cast(unsigned, f);
  return (u16)((u + 0x7fffu + ((u >> 16) & 1u)) >> 16);
}
__device__ __forceinline__ float bf2f(u16 h) {
  return __builtin_bit_cast(float, (unsigned)h << 16);
}
__device__ __forceinline__ f32x4 mfma16(u16x8 a, u16x8 b, f32x4 c) {
  return __builtin_amdgcn_mfma_f32_16x16x32_bf16(
      __builtin_bit_cast(bf16x8, a), __builtin_bit_cast(bf16x8, b), c, 0, 0, 0);
}
__device__ __forceinline__ void gld16(const void* g, void* l) {
  __builtin_amdgcn_global_load_lds(
      (const __attribute__((address_space(1))) void*)g,
      (__attribute__((address_space(3))) void*)l, 16, 0, 0);
}

// ---------- elementwise cast x -> bf16 ----------
__global__ __launch_bounds__(256) void k_cast_x(const float* __restrict__ x, u16* __restrict__ xb) {
  int i = blockIdx.x * 256 + threadIdx.x;
  float4 v = ((const float4*)x)[i];
  union { u16 u[4]; uint2 p; } o;
  o.u[0] = f2bf(v.x); o.u[1] = f2bf(v.y); o.u[2] = f2bf(v.z); o.u[3] = f2bf(v.w);
  ((uint2*)xb)[i] = o.p;
}

// ---------- tiled transpose+cast: w[K][N] fp32 -> wt[N][K(=2048 pitch)] bf16 ----------
__global__ __launch_bounds__(256) void k_wt(const float* __restrict__ w, u16* __restrict__ wt, int K, int N) {
  __shared__ float tile[32][33];
  int kb = blockIdx.y * 32, nb = blockIdx.x * 32;
  int tx = threadIdx.x, ty = threadIdx.y;
#pragma unroll
  for (int j = 0; j < 32; j += 8)
    tile[ty + j][tx] = w[(size_t)(kb + ty + j) * N + nb + tx];
  __syncthreads();
#pragma unroll
  for (int j = 0; j < 32; j += 8)
    wt[(size_t)(nb + ty + j) * K + kb + tx] = f2bf(tile[tx][ty + j]);
}

// ---------- 256xBN 8-phase GEMM: C[M][NT] = A[M][2048] * Bt[NT][2048]^T ----------
// Round-6: geometry, not schedule. r1-r5 showed schedule variants are all ~1160
// cyc/phase at 256x256 (MFMA 621 + LDS ~580 summed); the remaining first-order
// losses are (1) QKV grid 384 blocks = 1.5 rounds at 1 block/CU (75% eff) and
// (2) wave-tile 128x64's compute:LDS ratio. Fix: QKV uses BN=384 (wave-tile
// 128x96, acc[8][6]=192 AGPR-resident, 256 blocks = exactly 1 round, LDS=160KiB:
// A 4x[256][32]=64K + B 4x[384][32]=96K). WO keeps BN=256 (exact r3 path).
// Ledger (BN=384): loads/phase alternate A:2, B:3; per-tile in-flight peaks 15;
// vmcnt(10) at ph2/ph4 leaves the 4 half-stages after the confirmed half.
// Schedule, slot ring slot(t,kh)=(2t+kh)&3, chunk swizzle pos=c^((row>>1)&3)
// (conflicts==0, r2), and K accumulation order unchanged from r3.

#define STG_A(KK, SS) do {                                                   \
    _Pragma("unroll") for (int j_ = 0; j_ < 2; ++j_)                         \
      gld16(Ag + (size_t)(j_ * 128 + r0) * 2048 + (KK) + coff,               \
            As + (SS) * 8192 + j_ * 4096 + stl0);                            \
  } while (0)
#define STG_B(KK, SS) do {                                                   \
    _Pragma("unroll") for (int j_ = 0; j_ < BN / 128; ++j_)                  \
      gld16(Bg + (size_t)(j_ * 128 + r0) * 2048 + (KK) + coff,               \
            Bs + (SS) * (BN * 32) + j_ * 4096 + stl0);                       \
  } while (0)

#define VMW() do {                                                           \
    if constexpr (BN == 256) asm volatile("s_waitcnt vmcnt(8)" ::: "memory");\
    else                     asm volatile("s_waitcnt vmcnt(10)" ::: "memory");\
  } while (0)

#define PHASE(RS, MB, RB, SS, SK, SA, VM) do {                               \
    const u16* Ap_ = As + (RS) * 8192;                                       \
    _Pragma("unroll") for (int i_ = 0; i_ < 4; ++i_)                         \
      af[i_] = *(const u16x8*)(Ap_ + arow0 + ((MB) + i_) * 512);             \
    if (RB) {                                                                \
      const u16* Bp_ = Bs + (RS) * (BN * 32);                                \
      _Pragma("unroll") for (int i_ = 0; i_ < BN / 64; ++i_)                 \
        bf[i_] = *(const u16x8*)(Bp_ + brow0 + i_ * 512);                    \
    }                                                                        \
    if (SA) STG_A(SK, SS); else STG_B(SK, SS);                               \
    asm volatile("s_barrier" ::: "memory");                                  \
    asm volatile("s_waitcnt lgkmcnt(0)" ::: "memory");                       \
    __builtin_amdgcn_sched_barrier(0);                                       \
    __builtin_amdgcn_s_setprio(1);                                           \
    _Pragma("unroll") for (int i_ = 0; i_ < 4; ++i_)                         \
      _Pragma("unroll") for (int n_ = 0; n_ < BN / 64; ++n_)                 \
        acc[(MB) + i_][n_] = mfma16(af[i_], bf[n_], acc[(MB) + i_][n_]);     \
    __builtin_amdgcn_s_setprio(0);                                           \
    __builtin_amdgcn_sched_barrier(0);                                       \
    if (VM) VMW();                                                           \
    asm volatile("s_barrier" ::: "memory");                                  \
  } while (0)

template<int NT, int BN, bool F32OUT>
__global__ __launch_bounds__(512, 2) void k_gemm(const u16* __restrict__ A, const u16* __restrict__ Bt,
                                                 void* __restrict__ C) {
  __shared__ u16 As[4 * 8192];        // 64 KiB: 4 k-half slots [256][32]
  __shared__ u16 Bs[4 * (BN * 32)];   // 64 or 96 KiB: 4 k-half slots [BN][32]
  int id = blockIdx.x;
  int nwg = gridDim.x;                        // divisible by 8 for both grids
  id = (id & 7) * (nwg >> 3) + (id >> 3);     // XCD-contiguous (bijective: nwg%8==0)
  const int gx = NT / BN;
  int mb = (id / gx) * 256, nb = (id % gx) * BN;

  int t = threadIdx.x;
  int l = t & 63, L16 = l & 15, quad = l >> 4;
  int w = t >> 6, wm = w >> 2, wn = w & 3;    // 2x4 wave grid, wave tile 128x(BN/4)
  const int schunk = 8 * (quad ^ ((L16 >> 1) & 3));  // quad-pass-balanced read chunk
  const int arow0 = (wm * 128 + L16) * 32 + schunk;
  const int brow0 = (wn * (BN / 4) + L16) * 32 + schunk;
  const int r0 = t >> 2;                      // staging row within 128-row group
  const int coff = 8 * ((t & 3) ^ ((r0 >> 1) & 3));   // inverse-swizzled global chunk
  const int stl0 = (t & 448) * 8;             // wave-uniform LDS base (HW adds lane*16B)

  const u16* Ag = A + (size_t)mb * 2048;
  const u16* Bg = Bt + (size_t)nb * 2048;
  u16x8 af[4], bf[BN / 64];
  f32x4 acc[8][BN / 64] = {};

  // prologue: (0,k0)->s0, (0,k1)->s1, (1,k0)->s2; confirm (0,k0)
  STG_A(0, 0);  STG_B(0, 0);
  STG_A(32, 1); STG_B(32, 1);
  STG_A(64, 2); STG_B(64, 2);
  VMW();
  asm volatile("s_barrier" ::: "memory");

#pragma unroll 2
  for (int tt = 0; tt < 32; ++tt) {
    int rs0 = (2 * tt) & 3, rs1 = (2 * tt + 1) & 3;
    int ss1 = (2 * tt + 3) & 3;              // slot for (t+1,k1)
    int k1n = ((tt + 1) & 31) * 64 + 32;     // (t+1,k1); wraps tail (in-bounds)
    int k0n = ((tt + 2) & 31) * 64;          // (t+2,k0); wraps tail (in-bounds)
    PHASE(rs0, 0, true,  ss1, k1n, true,  false);  // read(t,k0) m0-3+B; stage A(t+1,k1)
    PHASE(rs0, 4, false, ss1, k1n, false, true);   // read(t,k0) m4-7;  stage B(t+1,k1); vmcnt
    PHASE(rs1, 0, true,  rs0, k0n, true,  false);  // read(t,k1) m0-3+B; stage A(t+2,k0)
    PHASE(rs1, 4, false, rs0, k0n, false, true);   // read(t,k1) m4-7;  stage B(t+2,k0); vmcnt
  }
  asm volatile("s_waitcnt vmcnt(0)" ::: "memory");  // drain tail garbage stages

#pragma unroll
  for (int m = 0; m < 8; ++m)
#pragma unroll
    for (int n = 0; n < BN / 64; ++n)
#pragma unroll
      for (int r = 0; r < 4; ++r) {
        int row = mb + wm * 128 + m * 16 + quad * 4 + r;
        int col = nb + wn * (BN / 4) + n * 16 + L16;
        if constexpr (F32OUT)
          ((float*)C)[(size_t)row * NT + col] = acc[m][n][r];
        else
          ((u16*)C)[(size_t)row * NT + col] = f2bf(acc[m][n][r]);
      }
}

// ---------- RoPE + scatter; Q pre-scaled by log2(e)/sqrt(HD) ----------
__global__ __launch_bounds__(256) void k_rope(const u16* __restrict__ qkv, const float* __restrict__ fc,
                                              const float* __restrict__ fs, u16* __restrict__ Q,
                                              u16* __restrict__ Kk) {
  const float SC = 0.1275174214f;  // log2(e)/sqrt(128), folded into Q
  int row = blockIdx.x;            // b*S + s
  int b = row >> 11, s = row & 2047;
  int t = threadIdx.x;
#pragma unroll
  for (int j = 0; j < 5; ++j) {
    int p = t + j * 256;           // pair index, 0..1279
    int i = p & 63;
    float c = fc[s * 64 + i], sn = fs[s * 64 + i];
    if (p < 1024) {
      int h = p >> 6;
      unsigned pr = *(const unsigned*)(qkv + (size_t)row * QKV_N + h * 128 + 2 * i);
      float xr = bf2f((u16)(pr & 0xffff)), xi = bf2f((u16)(pr >> 16));
      size_t o = (((size_t)(b * NH + h) * S_) + s) * HD + 2 * i;
      unsigned out = (unsigned)f2bf((xr * c - xi * sn) * SC) |
                     ((unsigned)f2bf((xr * sn + xi * c) * SC) << 16);
      *(unsigned*)(Q + o) = out;
    } else {
      int kh = (p - 1024) >> 6;
      unsigned pr = *(const unsigned*)(qkv + (size_t)row * QKV_N + 2048 + kh * 128 + 2 * i);
      float xr = bf2f((u16)(pr & 0xffff)), xi = bf2f((u16)(pr >> 16));
      size_t o = (((size_t)(b * NKV + kh) * S_) + s) * HD + 2 * i;
      unsigned out = (unsigned)f2bf(xr * c - xi * sn) | ((unsigned)f2bf(xr * sn + xi * c) << 16);
      *(unsigned*)(Kk + o) = out;
    }
  }
}

// ---------- V transpose: coalesced loads -> swizzled LDS -> u32-pair transposed reads ----------
__global__ __launch_bounds__(256) void k_vt(const u16* __restrict__ qkv, u16* __restrict__ Vt) {
  __shared__ u16 tile[64 * 128];       // [s][d], chunk-swizzled: chunk ^= s&15
  int blk = blockIdx.x;                // b*128 + kh*32 + sb
  int sb = blk & 31, kh = (blk >> 5) & 3, b = blk >> 7;
  int t = threadIdx.x;
  int s0 = sb * 64;
#pragma unroll
  for (int i = 0; i < 4; ++i) {
    int lin = i * 256 + t;
    int row = lin >> 4, c = lin & 15;
    u16x8 v = *(const u16x8*)(qkv + (size_t)(b * S_ + s0 + row) * QKV_N + 2560 + kh * HD + c * 8);
    *(u16x8*)(tile + row * 128 + ((c ^ (row & 15)) * 8)) = v;
  }
  __syncthreads();
#pragma unroll
  for (int i = 0; i < 2; ++i) {
    int u = i * 256 + t;
    int p = u >> 3, o = u & 7;         // d = 2p, 2p+1 ; s = o*8 .. o*8+7
    u16 lo[8], hi[8];
#pragma unroll
    for (int j = 0; j < 8; ++j) {
      int s = o * 8 + j;
      int cs = (p >> 2) ^ (s & 15);
      unsigned v = *(const unsigned*)(tile + s * 128 + cs * 8 + (p & 3) * 2);
      lo[j] = (u16)(v & 0xffff); hi[j] = (u16)(v >> 16);
    }
    size_t ob = ((size_t)(b * NKV + kh) * HD + 2 * p) * S_ + s0 + o * 8;
    *(u16x8*)(Vt + ob)      = *(u16x8*)lo;
    *(u16x8*)(Vt + ob + S_) = *(u16x8*)hi;
  }
}

// ---------- flash attention v6: R2 skeleton + S^T compute (b64 P writes) + hoisted LDS addrs ----------
__global__ __launch_bounds__(256) void k_attn(const u16* __restrict__ Q, const u16* __restrict__ Kg,
                                              const u16* __restrict__ Vt, u16* __restrict__ O) {
  int bx = blockIdx.x;
  int bh = bx >> 3, pr = bx & 7;
  int b = bh >> 4, h = bh & 15, kh = h >> 2;
  int t = threadIdx.x;
  int w = t >> 6, l = t & 63, L = l & 15, quad = l >> 4;

  __shared__ u16 Ks[64 * 128];         // [key][d], chunk ^= key&7
  __shared__ u16 Vs[128 * 64];         // [d][key], chunk ^= d&7
  __shared__ u16 Ps[4][32 * 72];       // per-wave P[q][key], pitch 72
  u16* Pw = &Ps[w][0];

  const u16* Qh = Q  + ((size_t)(b * NH  + h ) * S_) * HD;
  const u16* Kh = Kg + ((size_t)(b * NKV + kh) * S_) * HD;
  const u16* Vh = Vt + ((size_t)(b * NKV + kh) * HD) * S_;

  u16x8 ones;                          // bf16 1.0 B-fragment -> row sums in acc[.][8]
#pragma unroll
  for (int i = 0; i < 8; ++i) ones[i] = 0x3F80;

  // ---- hoisted LDS fragment offsets (u16 units; loop-invariant, imm offsets inside) ----
  int koff[4], voff[2];
#pragma unroll
  for (int kk = 0; kk < 4; ++kk) koff[kk] = 128 * L + 8 * ((4 * kk + quad) ^ (L & 7));
#pragma unroll
  for (int kc = 0; kc < 2; ++kc) voff[kc] = 64 * L + 8 * ((4 * kc + quad) ^ (L & 7));
  const int pread  = 72 * L + 8 * quad;   // + 1152*m + 32*kc (imm)
  const int pwrite = 72 * L + 4 * quad;   // + 1152*m + 16*n  (imm)

  // ---- hoisted staging offsets ----
  int kgo[4], vgo[4], klo[4], vlo[4];
#pragma unroll
  for (int i = 0; i < 4; ++i) {
    int lin = i * 256 + t;
    int row = lin >> 4, c = lin & 15;
    kgo[i] = row * HD + ((c ^ (row & 7)) * 8);
    int d = lin >> 3, c2 = lin & 7;
    vgo[i] = d * S_ + ((c2 ^ (d & 7)) * 8);
    klo[i] = (i * 256 + (t & 192)) * 8;
    vlo[i] = (i * 256 + (t & 192)) * 8;
  }

#pragma unroll 1
  for (int half = 0; half < 2; ++half) {
    int qb = half ? (15 - pr) : pr;
    int q0 = qb * 128 + w * 32;        // this wave's 32 query rows

    u16x8 qf[2][4];
#pragma unroll
    for (int m = 0; m < 2; ++m)
#pragma unroll
      for (int kk = 0; kk < 4; ++kk)
        qf[m][kk] = *(const u16x8*)(Qh + (size_t)(q0 + m * 16 + L) * HD + kk * 32 + quad * 8);

    f32x4 acc[2][9] = {};
    int ktiles = 2 * qb + 2;
#pragma unroll 1
    for (int kt = 0; kt < ktiles; ++kt) {
      int kbase = kt * 64;
      __syncthreads();
      const u16* Kt = Kh + (size_t)kbase * HD;
      const u16* Vg = Vh + kbase;
#pragma unroll
      for (int i = 0; i < 4; ++i) gld16(Kt + kgo[i], Ks + klo[i]);
#pragma unroll
      for (int i = 0; i < 4; ++i) gld16(Vg + vgo[i], Vs + vlo[i]);
      __syncthreads();
      if (kbase > q0 + 31) continue;   // fully masked for this wave; barriers stay uniform

      bool needMask = (kbase + 63 > q0);
      // S^T = K Q^T : A=K-frag, B=Q-frag -> lane holds 4 consecutive keys (rows), col=q
#pragma unroll
      for (int n = 0; n < 4; ++n) {
        f32x4 s0v = {}, s1v = {};
#pragma unroll
        for (int kk = 0; kk < 4; ++kk) {
          u16x8 kf = *(const u16x8*)(Ks + koff[kk] + 2048 * n);
          s0v = mfma16(kf, qf[0][kk], s0v);
          s1v = mfma16(kf, qf[1][kk], s1v);
        }
        // exp2 + mask + packed b64 P store: keys 16n+4quad+r, q = q0+16m+L
#pragma unroll
        for (int m = 0; m < 2; ++m) {
          f32x4 sv = m ? s1v : s0v;
          int qrow = q0 + m * 16 + L;
          unsigned eu[4];
#pragma unroll
          for (int r = 0; r < 4; ++r) {
            float e = exp2f(sv[r]);
            if (needMask) {
              int key = kbase + n * 16 + quad * 4 + r;
              e = (key <= qrow) ? e : 0.0f;
            }
            eu[r] = __builtin_bit_cast(unsigned, e);
          }
          uint2 pk;
          pk.x = __builtin_amdgcn_perm(eu[1], eu[0], 0x07060302u);  // bf16(e0)|bf16(e1)<<16 (trunc)
          pk.y = __builtin_amdgcn_perm(eu[3], eu[2], 0x07060302u);
          *(uint2*)(Pw + pwrite + 1152 * m + 16 * n) = pk;
        }
      }
      // O += P V ; row sums via register ones fragment into acc[.][8] (wave-private P)
#pragma unroll
      for (int kc = 0; kc < 2; ++kc) {
        u16x8 pf0 = *(const u16x8*)(Pw + pread + 32 * kc);
        u16x8 pf1 = *(const u16x8*)(Pw + pread + 1152 + 32 * kc);
#pragma unroll
        for (int nt = 0; nt < 8; ++nt) {
          u16x8 vf = *(const u16x8*)(Vs + voff[kc] + 1024 * nt);
          acc[0][nt] = mfma16(pf0, vf, acc[0][nt]);
          acc[1][nt] = mfma16(pf1, vf, acc[1][nt]);
        }
        acc[0][8] = mfma16(pf0, ones, acc[0][8]);
        acc[1][8] = mfma16(pf1, ones, acc[1][8]);
      }
    }
    // epilogue: normalize by ones-column sums (acc[m][8]), write [b][s][h*128+d]
#pragma unroll
    for (int m = 0; m < 2; ++m)
#pragma unroll
      for (int r = 0; r < 4; ++r) {
        float inv = 1.0f / acc[m][8][r];
        int qrow = q0 + m * 16 + quad * 4 + r;
#pragma unroll
        for (int nt = 0; nt < 8; ++nt) {
          int col = h * HD + nt * 16 + L;
          O[(size_t)(b * S_ + qrow) * D_ + col] = f2bf(acc[m][nt][r] * inv);
        }
      }
  }
}

extern "C" void kernel_launch(void* const* d_in, const int* in_sizes, int n_in,
                              void* d_out, int out_size, void* d_ws, size_t ws_size,
                              hipStream_t stream) {
  const float* x  = (const float*)d_in[0];
  const float* fc = (const float*)d_in[1];
  const float* fs = (const float*)d_in[2];
  const float* wq = (const float*)d_in[3];
  const float* wk = (const float*)d_in[4];
  const float* wv = (const float*)d_in[5];
  const float* wo = (const float*)d_in[6];
  float* out = (float*)d_out;

  u16* p = (u16*)d_ws;
  u16* xb    = p; p += (size_t)ROWS * D_;
  u16* wqkvT = p; p += (size_t)QKV_N * D_;
  u16* woT   = p; p += (size_t)D_ * D_;
  u16* qkv   = p; p += (size_t)ROWS * QKV_N;
  u16* Qr    = p; p += (size_t)ROWS * (NH * HD);
  u16* Kr    = p; p += (size_t)ROWS * (NKV * HD);
  u16* Vtr   = p; p += (size_t)ROWS * (NKV * HD);
  u16* AO    = p; p += (size_t)ROWS * D_;

  k_cast_x<<<dim3(ROWS * D_ / 1024), dim3(256), 0, stream>>>(x, xb);
  k_wt<<<dim3(64, 64), dim3(32, 8), 0, stream>>>(wq, wqkvT, 2048, 2048);
  k_wt<<<dim3(16, 64), dim3(32, 8), 0, stream>>>(wk, wqkvT + (size_t)2048 * 2048, 2048, 512);
  k_wt<<<dim3(16, 64), dim3(32, 8), 0, stream>>>(wv, wqkvT + (size_t)2560 * 2048, 2048, 512);
  k_wt<<<dim3(64, 64), dim3(32, 8), 0, stream>>>(wo, woT, 2048, 2048);
  k_gemm<QKV_N, 384, false><<<dim3((QKV_N / 384) * (ROWS / 256)), dim3(512), 0, stream>>>(xb, wqkvT, qkv);
  k_rope<<<dim3(ROWS), dim3(256), 0, stream>>>(qkv, fc, fs, Qr, Kr);
  k_vt<<<dim3(B_ * NKV * (S_ / 64)), dim3(256), 0, stream>>>(qkv, Vtr);
  k_attn<<<dim3(64 * 8), dim3(256), 0, stream>>>(Qr, Kr, Vtr, AO);
  k_gemm<D_, 256, true><<<dim3((D_ / 256) * (ROWS / 256)), dim3(512), 0, stream>>>(AO, woT, out);
}

// Round 7
// 421.978 us; speedup vs baseline: 1.2265x; 1.0579x over previous
//
#include <hip/hip_runtime.h>
#include <stdint.h>
#include <stddef.h>

#define B_ 4
#define S_ 2048
#define D_ 2048
#define NH 16
#define NKV 4
#define HD 128
#define QKV_N 3072
#define ROWS (B_*S_)

typedef unsigned short u16;
typedef __attribute__((ext_vector_type(8))) unsigned short u16x8;
typedef __attribute__((ext_vector_type(8))) __bf16 bf16x8;
typedef __attribute__((ext_vector_type(4))) float f32x4;

#if __has_builtin(__builtin_amdgcn_exp2f)
#define EXP2F(x) __builtin_amdgcn_exp2f(x)
#else
#define EXP2F(x) exp2f(x)
#endif

__device__ __forceinline__ u16 f2bf(float f) {
  unsigned u = __builtin_bit_cast(unsigned, f);
  return (u16)((u + 0x7fffu + ((u >> 16) & 1u)) >> 16);
}
__device__ __forceinline__ float bf2f(u16 h) {
  return __builtin_bit_cast(float, (unsigned)h << 16);
}
__device__ __forceinline__ f32x4 mfma16(u16x8 a, u16x8 b, f32x4 c) {
  return __builtin_amdgcn_mfma_f32_16x16x32_bf16(
      __builtin_bit_cast(bf16x8, a), __builtin_bit_cast(bf16x8, b), c, 0, 0, 0);
}
__device__ __forceinline__ void gld16(const void* g, void* l) {
  __builtin_amdgcn_global_load_lds(
      (const __attribute__((address_space(1))) void*)g,
      (__attribute__((address_space(3))) void*)l, 16, 0, 0);
}

// ---------- elementwise cast x -> bf16 ----------
__global__ __launch_bounds__(256) void k_cast_x(const float* __restrict__ x, u16* __restrict__ xb) {
  int i = blockIdx.x * 256 + threadIdx.x;
  float4 v = ((const float4*)x)[i];
  union { u16 u[4]; uint2 p; } o;
  o.u[0] = f2bf(v.x); o.u[1] = f2bf(v.y); o.u[2] = f2bf(v.z); o.u[3] = f2bf(v.w);
  ((uint2*)xb)[i] = o.p;
}

// ---------- tiled transpose+cast: w[K][N] fp32 -> wt[N][K(=2048 pitch)] bf16 ----------
__global__ __launch_bounds__(256) void k_wt(const float* __restrict__ w, u16* __restrict__ wt, int K, int N) {
  __shared__ float tile[32][33];
  int kb = blockIdx.y * 32, nb = blockIdx.x * 32;
  int tx = threadIdx.x, ty = threadIdx.y;
#pragma unroll
  for (int j = 0; j < 32; j += 8)
    tile[ty + j][tx] = w[(size_t)(kb + ty + j) * N + nb + tx];
  __syncthreads();
#pragma unroll
  for (int j = 0; j < 32; j += 8)
    wt[(size_t)(nb + ty + j) * K + kb + tx] = f2bf(tile[tx][ty + j]);
}

// ---------- 256xBN 8-phase GEMM (unchanged from round 6) ----------
#define STG_A(KK, SS) do {                                                   \
    _Pragma("unroll") for (int j_ = 0; j_ < 2; ++j_)                         \
      gld16(Ag + (size_t)(j_ * 128 + r0) * 2048 + (KK) + coff,               \
            As + (SS) * 8192 + j_ * 4096 + stl0);                            \
  } while (0)
#define STG_B(KK, SS) do {                                                   \
    _Pragma("unroll") for (int j_ = 0; j_ < BN / 128; ++j_)                  \
      gld16(Bg + (size_t)(j_ * 128 + r0) * 2048 + (KK) + coff,               \
            Bs + (SS) * (BN * 32) + j_ * 4096 + stl0);                       \
  } while (0)

#define VMW() do {                                                           \
    if constexpr (BN == 256) asm volatile("s_waitcnt vmcnt(8)" ::: "memory");\
    else                     asm volatile("s_waitcnt vmcnt(10)" ::: "memory");\
  } while (0)

#define PHASE(RS, MB, RB, SS, SK, SA, VM) do {                               \
    const u16* Ap_ = As + (RS) * 8192;                                       \
    _Pragma("unroll") for (int i_ = 0; i_ < 4; ++i_)                         \
      af[i_] = *(const u16x8*)(Ap_ + arow0 + ((MB) + i_) * 512);             \
    if (RB) {                                                                \
      const u16* Bp_ = Bs + (RS) * (BN * 32);                                \
      _Pragma("unroll") for (int i_ = 0; i_ < BN / 64; ++i_)                 \
        bf[i_] = *(const u16x8*)(Bp_ + brow0 + i_ * 512);                    \
    }                                                                        \
    if (SA) STG_A(SK, SS); else STG_B(SK, SS);                               \
    asm volatile("s_barrier" ::: "memory");                                  \
    asm volatile("s_waitcnt lgkmcnt(0)" ::: "memory");                       \
    __builtin_amdgcn_sched_barrier(0);                                       \
    __builtin_amdgcn_s_setprio(1);                                           \
    _Pragma("unroll") for (int i_ = 0; i_ < 4; ++i_)                         \
      _Pragma("unroll") for (int n_ = 0; n_ < BN / 64; ++n_)                 \
        acc[(MB) + i_][n_] = mfma16(af[i_], bf[n_], acc[(MB) + i_][n_]);     \
    __builtin_amdgcn_s_setprio(0);                                           \
    __builtin_amdgcn_sched_barrier(0);                                       \
    if (VM) VMW();                                                           \
    asm volatile("s_barrier" ::: "memory");                                  \
  } while (0)

template<int NT, int BN, bool F32OUT>
__global__ __launch_bounds__(512, 2) void k_gemm(const u16* __restrict__ A, const u16* __restrict__ Bt,
                                                 void* __restrict__ C) {
  __shared__ u16 As[4 * 8192];        // 64 KiB: 4 k-half slots [256][32]
  __shared__ u16 Bs[4 * (BN * 32)];   // 64 or 96 KiB: 4 k-half slots [BN][32]
  int id = blockIdx.x;
  int nwg = gridDim.x;                        // divisible by 8 for both grids
  id = (id & 7) * (nwg >> 3) + (id >> 3);     // XCD-contiguous (bijective: nwg%8==0)
  const int gx = NT / BN;
  int mb = (id / gx) * 256, nb = (id % gx) * BN;

  int t = threadIdx.x;
  int l = t & 63, L16 = l & 15, quad = l >> 4;
  int w = t >> 6, wm = w >> 2, wn = w & 3;    // 2x4 wave grid, wave tile 128x(BN/4)
  const int schunk = 8 * (quad ^ ((L16 >> 1) & 3));  // quad-pass-balanced read chunk
  const int arow0 = (wm * 128 + L16) * 32 + schunk;
  const int brow0 = (wn * (BN / 4) + L16) * 32 + schunk;
  const int r0 = t >> 2;                      // staging row within 128-row group
  const int coff = 8 * ((t & 3) ^ ((r0 >> 1) & 3));   // inverse-swizzled global chunk
  const int stl0 = (t & 448) * 8;             // wave-uniform LDS base (HW adds lane*16B)

  const u16* Ag = A + (size_t)mb * 2048;
  const u16* Bg = Bt + (size_t)nb * 2048;
  u16x8 af[4], bf[BN / 64];
  f32x4 acc[8][BN / 64] = {};

  // prologue: (0,k0)->s0, (0,k1)->s1, (1,k0)->s2; confirm (0,k0)
  STG_A(0, 0);  STG_B(0, 0);
  STG_A(32, 1); STG_B(32, 1);
  STG_A(64, 2); STG_B(64, 2);
  VMW();
  asm volatile("s_barrier" ::: "memory");

#pragma unroll 2
  for (int tt = 0; tt < 32; ++tt) {
    int rs0 = (2 * tt) & 3, rs1 = (2 * tt + 1) & 3;
    int ss1 = (2 * tt + 3) & 3;              // slot for (t+1,k1)
    int k1n = ((tt + 1) & 31) * 64 + 32;     // (t+1,k1); wraps tail (in-bounds)
    int k0n = ((tt + 2) & 31) * 64;          // (t+2,k0); wraps tail (in-bounds)
    PHASE(rs0, 0, true,  ss1, k1n, true,  false);  // read(t,k0) m0-3+B; stage A(t+1,k1)
    PHASE(rs0, 4, false, ss1, k1n, false, true);   // read(t,k0) m4-7;  stage B(t+1,k1); vmcnt
    PHASE(rs1, 0, true,  rs0, k0n, true,  false);  // read(t,k1) m0-3+B; stage A(t+2,k0)
    PHASE(rs1, 4, false, rs0, k0n, false, true);   // read(t,k1) m4-7;  stage B(t+2,k0); vmcnt
  }
  asm volatile("s_waitcnt vmcnt(0)" ::: "memory");  // drain tail garbage stages

#pragma unroll
  for (int m = 0; m < 8; ++m)
#pragma unroll
    for (int n = 0; n < BN / 64; ++n)
#pragma unroll
      for (int r = 0; r < 4; ++r) {
        int row = mb + wm * 128 + m * 16 + quad * 4 + r;
        int col = nb + wn * (BN / 4) + n * 16 + L16;
        if constexpr (F32OUT)
          ((float*)C)[(size_t)row * NT + col] = acc[m][n][r];
        else
          ((u16*)C)[(size_t)row * NT + col] = f2bf(acc[m][n][r]);
      }
}

// ---------- RoPE + scatter; Q pre-scaled by log2(e)/sqrt(HD) ----------
__global__ __launch_bounds__(256) void k_rope(const u16* __restrict__ qkv, const float* __restrict__ fc,
                                              const float* __restrict__ fs, u16* __restrict__ Q,
                                              u16* __restrict__ Kk) {
  const float SC = 0.1275174214f;  // log2(e)/sqrt(128), folded into Q
  int row = blockIdx.x;            // b*S + s
  int b = row >> 11, s = row & 2047;
  int t = threadIdx.x;
#pragma unroll
  for (int j = 0; j < 5; ++j) {
    int p = t + j * 256;           // pair index, 0..1279
    int i = p & 63;
    float c = fc[s * 64 + i], sn = fs[s * 64 + i];
    if (p < 1024) {
      int h = p >> 6;
      unsigned pr = *(const unsigned*)(qkv + (size_t)row * QKV_N + h * 128 + 2 * i);
      float xr = bf2f((u16)(pr & 0xffff)), xi = bf2f((u16)(pr >> 16));
      size_t o = (((size_t)(b * NH + h) * S_) + s) * HD + 2 * i;
      unsigned out = (unsigned)f2bf((xr * c - xi * sn) * SC) |
                     ((unsigned)f2bf((xr * sn + xi * c) * SC) << 16);
      *(unsigned*)(Q + o) = out;
    } else {
      int kh = (p - 1024) >> 6;
      unsigned pr = *(const unsigned*)(qkv + (size_t)row * QKV_N + 2048 + kh * 128 + 2 * i);
      float xr = bf2f((u16)(pr & 0xffff)), xi = bf2f((u16)(pr >> 16));
      size_t o = (((size_t)(b * NKV + kh) * S_) + s) * HD + 2 * i;
      unsigned out = (unsigned)f2bf(xr * c - xi * sn) | ((unsigned)f2bf(xr * sn + xi * c) << 16);
      *(unsigned*)(Kk + o) = out;
    }
  }
}

// ---------- V transpose: coalesced loads -> swizzled LDS -> u32-pair transposed reads ----------
__global__ __launch_bounds__(256) void k_vt(const u16* __restrict__ qkv, u16* __restrict__ Vt) {
  __shared__ u16 tile[64 * 128];       // [s][d], chunk-swizzled: chunk ^= s&15
  int blk = blockIdx.x;                // b*128 + kh*32 + sb
  int sb = blk & 31, kh = (blk >> 5) & 3, b = blk >> 7;
  int t = threadIdx.x;
  int s0 = sb * 64;
#pragma unroll
  for (int i = 0; i < 4; ++i) {
    int lin = i * 256 + t;
    int row = lin >> 4, c = lin & 15;
    u16x8 v = *(const u16x8*)(qkv + (size_t)(b * S_ + s0 + row) * QKV_N + 2560 + kh * HD + c * 8);
    *(u16x8*)(tile + row * 128 + ((c ^ (row & 15)) * 8)) = v;
  }
  __syncthreads();
#pragma unroll
  for (int i = 0; i < 2; ++i) {
    int u = i * 256 + t;
    int p = u >> 3, o = u & 7;         // d = 2p, 2p+1 ; s = o*8 .. o*8+7
    u16 lo[8], hi[8];
#pragma unroll
    for (int j = 0; j < 8; ++j) {
      int s = o * 8 + j;
      int cs = (p >> 2) ^ (s & 15);
      unsigned v = *(const unsigned*)(tile + s * 128 + cs * 8 + (p & 3) * 2);
      lo[j] = (u16)(v & 0xffff); hi[j] = (u16)(v >> 16);
    }
    size_t ob = ((size_t)(b * NKV + kh) * HD + 2 * p) * S_ + s0 + o * 8;
    *(u16x8*)(Vt + ob)      = *(u16x8*)lo;
    *(u16x8*)(Vt + ob + S_) = *(u16x8*)hi;
  }
}

// ---------- flash attention v7: KVBLK=32, K+V double-buffered pipeline ----------
// r6 profile: attn = top steady dispatch (118.5us, MfmaUtil 26%, VALUBusy 47%).
// Defect: per-tile {sync; stage K,V; sync; compute} -- staging serial with compute.
// v7: 32-key tiles, 2 buffers each for K,V (LDS 16K+16K+10K=42KiB, 2 blocks/CU);
// per tile: {barrier A; issue stage(kt+1)->buf^1; vmcnt(4) confirms stage(kt);
// barrier B; compute(kt)}. Stage has a full tile (~700cyc) to land. Tail stages
// wrap to k=0 (in-bounds garbage), drained by vmcnt(0)+barrier at half end.
// P pitch 72->40 ((5L+q)%8 distinct -> conflict-free b128/b64). exp2 via raw
// v_exp_f32 builtin (VALU cut). Barriers are raw s_barrier (NOT __syncthreads:
// that drains vmcnt(0) and would kill the prefetch).
__global__ __launch_bounds__(256) void k_attn(const u16* __restrict__ Q, const u16* __restrict__ Kg,
                                              const u16* __restrict__ Vt, u16* __restrict__ O) {
  int bx = blockIdx.x;
  int bh = bx >> 3, pr = bx & 7;
  int b = bh >> 4, h = bh & 15, kh = h >> 2;
  int t = threadIdx.x;
  int w = t >> 6, l = t & 63, L = l & 15, quad = l >> 4;

  __shared__ u16 Ks[2][32 * 128];      // [buf][key][d], chunk ^= key&7
  __shared__ u16 Vs[2][128 * 32];      // [buf][d][key], chunk ^= (d>>1)&3
  __shared__ u16 Ps[4][32 * 40];       // per-wave P[q][key], pitch 40
  u16* Pw = &Ps[w][0];

  const u16* Qh = Q  + ((size_t)(b * NH  + h ) * S_) * HD;
  const u16* Kh = Kg + ((size_t)(b * NKV + kh) * S_) * HD;
  const u16* Vh = Vt + ((size_t)(b * NKV + kh) * HD) * S_;

  u16x8 ones;                          // bf16 1.0 B-fragment -> row sums in acc[.][8]
#pragma unroll
  for (int i = 0; i < 8; ++i) ones[i] = 0x3F80;

  // hoisted LDS fragment offsets (u16 units)
  int koff[4];
#pragma unroll
  for (int kk = 0; kk < 4; ++kk) koff[kk] = 128 * L + 8 * ((4 * kk + quad) ^ (L & 7));
  const int voff   = 32 * L + 8 * (quad ^ ((L >> 1) & 3));  // + 512*nt (imm)
  const int pread  = 40 * L + 8 * quad;   // + 640*m (imm)
  const int pwrite = 40 * L + 4 * quad;   // + 640*m + 16*n (imm)

  // staging offsets: K tile 32x128 (512 chunks), V tile 128x32 (512 chunks)
  int kgo[2], vgo[2], slo[2];
#pragma unroll
  for (int i = 0; i < 2; ++i) {
    int lin = i * 256 + t;
    int kr = lin >> 4, kc = lin & 15;
    kgo[i] = kr * HD + ((kc ^ (kr & 7)) * 8);
    int vd = lin >> 2, vc = lin & 3;
    vgo[i] = vd * S_ + ((vc ^ ((vd >> 1) & 3)) * 8);
    slo[i] = (i * 256 + (t & 192)) * 8;  // wave-uniform LDS base
  }

#pragma unroll 1
  for (int half = 0; half < 2; ++half) {
    int qb = half ? (15 - pr) : pr;
    int q0 = qb * 128 + w * 32;        // this wave's 32 query rows

    u16x8 qf[2][4];
#pragma unroll
    for (int m = 0; m < 2; ++m)
#pragma unroll
      for (int kk = 0; kk < 4; ++kk)
        qf[m][kk] = *(const u16x8*)(Qh + (size_t)(q0 + m * 16 + L) * HD + kk * 32 + quad * 8);
    asm volatile("s_waitcnt vmcnt(0)" ::: "memory");  // qf resident before loop
    __builtin_amdgcn_sched_barrier(0);

    f32x4 acc[2][9] = {};
    int ktiles = 4 * qb + 4;           // block-uniform
    // prologue: stage tile 0 -> buf 0
#pragma unroll
    for (int i = 0; i < 2; ++i) gld16(Kh + kgo[i], &Ks[0][0] + slo[i]);
#pragma unroll
    for (int i = 0; i < 2; ++i) gld16(Vh + vgo[i], &Vs[0][0] + slo[i]);

#pragma unroll 2
    for (int kt = 0; kt < ktiles; ++kt) {
      int kbase = kt * 32;
      int cur = kt & 1;
      asm volatile("s_barrier" ::: "memory");          // A: compute(kt-1) done block-wide
      int kb2 = (32 * (kt + 1)) & (S_ - 1);            // tail wraps (in-bounds garbage)
      const u16* Kt = Kh + (size_t)kb2 * HD;
      const u16* Vg = Vh + kb2;
      u16* Kn = &Ks[cur ^ 1][0];
      u16* Vn = &Vs[cur ^ 1][0];
#pragma unroll
      for (int i = 0; i < 2; ++i) gld16(Kt + kgo[i], Kn + slo[i]);
#pragma unroll
      for (int i = 0; i < 2; ++i) gld16(Vg + vgo[i], Vn + slo[i]);
      asm volatile("s_waitcnt vmcnt(4)" ::: "memory"); // own stage(kt) complete
      asm volatile("s_barrier" ::: "memory");          // B: stage(kt) visible block-wide
      if (kbase > q0 + 31) continue;   // fully masked for this wave; barriers stay uniform

      bool needMask = (kbase + 31 > q0);
      const u16* Kc = &Ks[cur][0];
      const u16* Vc = &Vs[cur][0];
      // S^T = K Q^T : lane holds keys 16n+4quad+r, col q = q0+16m+L
#pragma unroll
      for (int n = 0; n < 2; ++n) {
        f32x4 s0v = {}, s1v = {};
#pragma unroll
        for (int kk = 0; kk < 4; ++kk) {
          u16x8 kf = *(const u16x8*)(Kc + koff[kk] + 2048 * n);
          s0v = mfma16(kf, qf[0][kk], s0v);
          s1v = mfma16(kf, qf[1][kk], s1v);
        }
#pragma unroll
        for (int m = 0; m < 2; ++m) {
          f32x4 sv = m ? s1v : s0v;
          int qrow = q0 + m * 16 + L;
          unsigned eu[4];
#pragma unroll
          for (int r = 0; r < 4; ++r) {
            float e = EXP2F(sv[r]);
            if (needMask) {
              int key = kbase + n * 16 + quad * 4 + r;
              e = (key <= qrow) ? e : 0.0f;
            }
            eu[r] = __builtin_bit_cast(unsigned, e);
          }
          uint2 pk;
          pk.x = __builtin_amdgcn_perm(eu[1], eu[0], 0x07060302u);  // bf16 trunc pack
          pk.y = __builtin_amdgcn_perm(eu[3], eu[2], 0x07060302u);
          *(uint2*)(Pw + pwrite + 640 * m + 16 * n) = pk;
        }
      }
      // O += P V ; row sums via ones fragment into acc[.][8] (wave-private P)
      u16x8 pf0 = *(const u16x8*)(Pw + pread);
      u16x8 pf1 = *(const u16x8*)(Pw + pread + 640);
#pragma unroll
      for (int nt = 0; nt < 8; ++nt) {
        u16x8 vf = *(const u16x8*)(Vc + voff + 512 * nt);
        acc[0][nt] = mfma16(pf0, vf, acc[0][nt]);
        acc[1][nt] = mfma16(pf1, vf, acc[1][nt]);
      }
      acc[0][8] = mfma16(pf0, ones, acc[0][8]);
      acc[1][8] = mfma16(pf1, ones, acc[1][8]);
    }
    asm volatile("s_waitcnt vmcnt(0)" ::: "memory");   // drain tail garbage stages
    asm volatile("s_barrier" ::: "memory");

    // epilogue: normalize by ones-column sums (acc[m][8]), write [b][s][h*128+d]
#pragma unroll
    for (int m = 0; m < 2; ++m)
#pragma unroll
      for (int r = 0; r < 4; ++r) {
        float inv = 1.0f / acc[m][8][r];
        int qrow = q0 + m * 16 + quad * 4 + r;
#pragma unroll
        for (int nt = 0; nt < 8; ++nt) {
          int col = h * HD + nt * 16 + L;
          O[(size_t)(b * S_ + qrow) * D_ + col] = f2bf(acc[m][nt][r] * inv);
        }
      }
  }
}

extern "C" void kernel_launch(void* const* d_in, const int* in_sizes, int n_in,
                              void* d_out, int out_size, void* d_ws, size_t ws_size,
                              hipStream_t stream) {
  const float* x  = (const float*)d_in[0];
  const float* fc = (const float*)d_in[1];
  const float* fs = (const float*)d_in[2];
  const float* wq = (const float*)d_in[3];
  const float* wk = (const float*)d_in[4];
  const float* wv = (const float*)d_in[5];
  const float* wo = (const float*)d_in[6];
  float* out = (float*)d_out;

  u16* p = (u16*)d_ws;
  u16* xb    = p; p += (size_t)ROWS * D_;
  u16* wqkvT = p; p += (size_t)QKV_N * D_;
  u16* woT   = p; p += (size_t)D_ * D_;
  u16* qkv   = p; p += (size_t)ROWS * QKV_N;
  u16* Qr    = p; p += (size_t)ROWS * (NH * HD);
  u16* Kr    = p; p += (size_t)ROWS * (NKV * HD);
  u16* Vtr   = p; p += (size_t)ROWS * (NKV * HD);
  u16* AO    = p; p += (size_t)ROWS * D_;

  k_cast_x<<<dim3(ROWS * D_ / 1024), dim3(256), 0, stream>>>(x, xb);
  k_wt<<<dim3(64, 64), dim3(32, 8), 0, stream>>>(wq, wqkvT, 2048, 2048);
  k_wt<<<dim3(16, 64), dim3(32, 8), 0, stream>>>(wk, wqkvT + (size_t)2048 * 2048, 2048, 512);
  k_wt<<<dim3(16, 64), dim3(32, 8), 0, stream>>>(wv, wqkvT + (size_t)2560 * 2048, 2048, 512);
  k_wt<<<dim3(64, 64), dim3(32, 8), 0, stream>>>(wo, woT, 2048, 2048);
  k_gemm<QKV_N, 384, false><<<dim3((QKV_N / 384) * (ROWS / 256)), dim3(512), 0, stream>>>(xb, wqkvT, qkv);
  k_rope<<<dim3(ROWS), dim3(256), 0, stream>>>(qkv, fc, fs, Qr, Kr);
  k_vt<<<dim3(B_ * NKV * (S_ / 64)), dim3(256), 0, stream>>>(qkv, Vtr);
  k_attn<<<dim3(64 * 8), dim3(256), 0, stream>>>(Qr, Kr, Vtr, AO);
  k_gemm<D_, 256, true><<<dim3((D_ / 256) * (ROWS / 256)), dim3(512), 0, stream>>>(AO, woT, out);
}